// Round 2
// baseline (466.260 us; speedup 1.0000x reference)
//
#include <hip/hip_runtime.h>

#define C_CH 256  // channels, fixed by the problem

template<int P, int CPT>
__global__ __launch_bounds__(256) void roi_align_kernel(
    const float* __restrict__ feat, const float* __restrict__ rois,
    float* __restrict__ out, int N, int H, int W, float scale)
{
    constexpr int CG = C_CH / CPT;
    int tid = blockIdx.x * blockDim.x + threadIdx.x;
    int total = N * CG * P * P;
    if (tid >= total) return;

    int pw = tid % P;
    int t  = tid / P;
    int ph = t % P;
    t /= P;
    int cg = t % CG;
    int n  = t / CG;

    const float* r = rois + n * 5;
    int b = (int)r[0];
    float x1 = fmaf(r[1], scale, -0.5f);
    float y1 = fmaf(r[2], scale, -0.5f);
    float x2 = fmaf(r[3], scale, -0.5f);
    float y2 = fmaf(r[4], scale, -0.5f);
    float bin_h = (y2 - y1) * (1.0f / P);
    float bin_w = (x2 - x1) * (1.0f / P);

    float acc[CPT];
#pragma unroll
    for (int j = 0; j < CPT; ++j) acc[j] = 0.0f;

    const int HW = H * W;
    const float* fp = feat + ((size_t)b * C_CH + (size_t)cg * CPT) * HW;
    const float Hm1 = (float)(H - 1), Wm1 = (float)(W - 1);
    const float Hf = (float)H, Wf = (float)W;

#pragma unroll
    for (int iy = 0; iy < 2; ++iy) {
        float gy = (float)ph + (iy ? 0.75f : 0.25f);
        float yy = fmaf(gy, bin_h, y1);
        bool vy = (yy > -1.0f) && (yy < Hf);
        float yc = fminf(fmaxf(yy, 0.0f), Hm1);
        float y0f = floorf(yc);
        int   y0  = (int)y0f;
        float ly  = yc - y0f, hy = 1.0f - ly;
        int   y1i = min(y0 + 1, H - 1);
        int ro0 = y0 * W, ro1 = y1i * W;
#pragma unroll
        for (int ix = 0; ix < 2; ++ix) {
            float gx = (float)pw + (ix ? 0.75f : 0.25f);
            float xx = fmaf(gx, bin_w, x1);
            bool v = vy && (xx > -1.0f) && (xx < Wf);
            float xc = fminf(fmaxf(xx, 0.0f), Wm1);
            float x0f = floorf(xc);
            int   x0  = (int)x0f;
            float lx  = xc - x0f, hx = 1.0f - lx;
            int   x1i = min(x0 + 1, W - 1);
            float q = v ? 0.25f : 0.0f;  // fold validity + mean divisor into weights
            float w00 = hy * hx * q, w01 = hy * lx * q;
            float w10 = ly * hx * q, w11 = ly * lx * q;
            int o00 = ro0 + x0, o01 = ro0 + x1i;
            int o10 = ro1 + x0, o11 = ro1 + x1i;
#pragma unroll
            for (int j = 0; j < CPT; ++j) {
                const float* pj = fp + j * HW;
                acc[j] = fmaf(w00, pj[o00], acc[j]);
                acc[j] = fmaf(w01, pj[o01], acc[j]);
                acc[j] = fmaf(w10, pj[o10], acc[j]);
                acc[j] = fmaf(w11, pj[o11], acc[j]);
            }
        }
    }

    float* op = out + (((size_t)n * C_CH + (size_t)cg * CPT) * P + ph) * P + pw;
#pragma unroll
    for (int j = 0; j < CPT; ++j) op[(size_t)j * P * P] = acc[j];
}

extern "C" void kernel_launch(void* const* d_in, const int* in_sizes, int n_in,
                              void* d_out, int out_size, void* d_ws, size_t ws_size,
                              hipStream_t stream) {
    const float* feat1 = (const float*)d_in[0];  // (2,256,256,256)
    const float* feat2 = (const float*)d_in[1];  // (2,256,128,128)
    const float* feat3 = (const float*)d_in[2];  // (2,256,64,64)
    const float* rois  = (const float*)d_in[3];  // (N,5)
    const int N = in_sizes[3] / 5;               // 128

    float* out1 = (float*)d_out;
    float* out2 = out1 + (size_t)N * C_CH * 28 * 28;
    float* out3 = out2 + (size_t)N * C_CH * 14 * 14;

    constexpr int CPT = 4;
    constexpr int BLK = 256;

    {   // level 1: stride 4, 256x256, P=28
        int total = N * (C_CH / CPT) * 28 * 28;
        roi_align_kernel<28, CPT><<<(total + BLK - 1) / BLK, BLK, 0, stream>>>(
            feat1, rois, out1, N, 256, 256, 0.25f);
    }
    {   // level 2: stride 8, 128x128, P=14
        int total = N * (C_CH / CPT) * 14 * 14;
        roi_align_kernel<14, CPT><<<(total + BLK - 1) / BLK, BLK, 0, stream>>>(
            feat2, rois, out2, N, 128, 128, 0.125f);
    }
    {   // level 3: stride 16, 64x64, P=7
        int total = N * (C_CH / CPT) * 7 * 7;
        roi_align_kernel<7, CPT><<<(total + BLK - 1) / BLK, BLK, 0, stream>>>(
            feat3, rois, out3, N, 64, 64, 0.0625f);
    }
}

// Round 3
// 435.843 us; speedup vs baseline: 1.0698x; 1.0698x over previous
//
#include <hip/hip_runtime.h>

#define C_CH 256  // channels, fixed by the problem

// ---------------- Phase 1: NCHW -> NHWC transpose ----------------
// in: (B, C_CH, HW) viewed as C x HW matrix per batch; out: (B, HW, C_CH).
// 64(hw) x 64(c) tile, float4 global load/store, rotate-swizzled LDS
// (bank = (c+hw)&63 -> conflict-free scalar LDS on both phases).
__global__ __launch_bounds__(256) void nchw_to_nhwc(
    const float* __restrict__ in, float* __restrict__ out, int HW)
{
    __shared__ float lds[64 * 64];
    int ct = blockIdx.y & 3;          // c tile (C_CH/64 = 4)
    int b  = blockIdx.y >> 2;
    int hw0 = blockIdx.x << 6;
    int c0  = ct << 6;
    const float* ip = in  + (size_t)b * C_CH * HW;
    float*       op = out + (size_t)b * HW * C_CH;

    int t   = threadIdx.x;
    int q   = t & 15;                 // quad index 0..15
    int r0  = t >> 4;                 // 0..15

    // load: float4 along hw (coalesced), scatter into rotated LDS
#pragma unroll
    for (int k = 0; k < 4; ++k) {
        int c_local = r0 + (k << 4);
        const float4 v = *reinterpret_cast<const float4*>(
            ip + (size_t)(c0 + c_local) * HW + hw0 + (q << 2));
#pragma unroll
        for (int i = 0; i < 4; ++i) {
            int hw_local = (q << 2) + i;
            lds[(hw_local << 6) + ((c_local + hw_local) & 63)] = ((const float*)&v)[i];
        }
    }
    __syncthreads();
    // store: float4 along c (coalesced)
#pragma unroll
    for (int k = 0; k < 4; ++k) {
        int hw_local = r0 + (k << 4);
        float4 v;
#pragma unroll
        for (int j = 0; j < 4; ++j) {
            int c_local = (q << 2) + j;
            ((float*)&v)[j] = lds[(hw_local << 6) + ((c_local + hw_local) & 63)];
        }
        *reinterpret_cast<float4*>(
            op + (size_t)(hw0 + hw_local) * C_CH + c0 + (q << 2)) = v;
    }
}

// ---------------- Phase 2: gather from NHWC ----------------
// Block = 256 threads = 4 waves. Lane l covers channels 4l..4l+3 (float4).
// Each wave handles one sample position (n, ph, pw) at a time: 16 weighted
// corner loads, each a fully-coalesced 1KB wave read from NHWC.
// POS positions per block (28 = 1x28 | 2x14 | -, 49 = 7x7 full ROI).
template<int P, int POS>
__global__ __launch_bounds__(256) void roi_gather_nhwc(
    const float* __restrict__ nhwc, const float* __restrict__ rois,
    float* __restrict__ out, int H, int W, float scale)
{
    constexpr int PITCH = 260;  // floats per position row; 260*4B = 1040B (16B aligned)
    __shared__ float lds[POS * PITCH];

    const int n   = blockIdx.x;
    const int ph0 = blockIdx.y * (POS / P);
    const int lane = threadIdx.x & 63;
    const int wid  = threadIdx.x >> 6;
    const int c4   = lane << 2;

    const float* r = rois + n * 5;
    const int b = (int)r[0];
    const float x1 = fmaf(r[1], scale, -0.5f);
    const float y1 = fmaf(r[2], scale, -0.5f);
    const float x2 = fmaf(r[3], scale, -0.5f);
    const float y2 = fmaf(r[4], scale, -0.5f);
    const float bin_h = (y2 - y1) * (1.0f / P);
    const float bin_w = (x2 - x1) * (1.0f / P);

    const float Hm1 = (float)(H - 1), Wm1 = (float)(W - 1);
    const float Hf = (float)H, Wf = (float)W;
    const float* fb = nhwc + (size_t)b * H * W * C_CH;

    for (int pos = wid; pos < POS; pos += 4) {
        int ph = ph0 + pos / P;
        int pw = pos % P;

        float w[16];
        int   offc[16];
#pragma unroll
        for (int iy = 0; iy < 2; ++iy) {
            float gy = (float)ph + (iy ? 0.75f : 0.25f);
            float yy = fmaf(gy, bin_h, y1);
            bool vy = (yy > -1.0f) && (yy < Hf);
            float yc = fminf(fmaxf(yy, 0.0f), Hm1);
            float y0f = floorf(yc);
            int   y0  = (int)y0f;
            float ly  = yc - y0f, hy = 1.0f - ly;
            int   y1i = min(y0 + 1, H - 1);
            int ro0 = y0 * W, ro1 = y1i * W;
#pragma unroll
            for (int ix = 0; ix < 2; ++ix) {
                float gx = (float)pw + (ix ? 0.75f : 0.25f);
                float xx = fmaf(gx, bin_w, x1);
                bool v = vy && (xx > -1.0f) && (xx < Wf);
                float xc = fminf(fmaxf(xx, 0.0f), Wm1);
                float x0f = floorf(xc);
                int   x0  = (int)x0f;
                float lx  = xc - x0f, hx = 1.0f - lx;
                int   x1i = min(x0 + 1, W - 1);
                float q = v ? 0.25f : 0.0f;
                int s = ((iy << 1) + ix) << 2;
                w[s + 0] = hy * hx * q;  offc[s + 0] = ((ro0 + x0 ) << 8) + c4;
                w[s + 1] = hy * lx * q;  offc[s + 1] = ((ro0 + x1i) << 8) + c4;
                w[s + 2] = ly * hx * q;  offc[s + 2] = ((ro1 + x0 ) << 8) + c4;
                w[s + 3] = ly * lx * q;  offc[s + 3] = ((ro1 + x1i) << 8) + c4;
            }
        }

        float4 acc = {0.f, 0.f, 0.f, 0.f};
#pragma unroll
        for (int m = 0; m < 16; ++m) {
            const float4 v = *reinterpret_cast<const float4*>(fb + (size_t)(unsigned)offc[m]);
            acc.x = fmaf(w[m], v.x, acc.x);
            acc.y = fmaf(w[m], v.y, acc.y);
            acc.z = fmaf(w[m], v.z, acc.z);
            acc.w = fmaf(w[m], v.w, acc.w);
        }
        *reinterpret_cast<float4*>(&lds[pos * PITCH + c4]) = acc;
    }
    __syncthreads();

    // write-out: out[n][c][ph0.. ][..] — per channel c the POS values are a
    // contiguous run starting at ph0*P. Consecutive lanes -> consecutive pos.
    const size_t obase = (size_t)n * C_CH * P * P + (size_t)ph0 * P;
    for (int i = threadIdx.x; i < C_CH * POS; i += 256) {
        int c = i / POS;
        int pos = i - c * POS;
        out[obase + (size_t)c * (P * P) + pos] = lds[pos * PITCH + c];
    }
}

// ---------------- Fallback: direct NCHW kernel (round-1, verified) ----------------
template<int P, int CPT>
__global__ __launch_bounds__(256) void roi_align_direct(
    const float* __restrict__ feat, const float* __restrict__ rois,
    float* __restrict__ out, int N, int H, int W, float scale)
{
    constexpr int CG = C_CH / CPT;
    int tid = blockIdx.x * blockDim.x + threadIdx.x;
    int total = N * CG * P * P;
    if (tid >= total) return;

    int pw = tid % P;
    int t  = tid / P;
    int ph = t % P;
    t /= P;
    int cg = t % CG;
    int n  = t / CG;

    const float* r = rois + n * 5;
    int b = (int)r[0];
    float x1 = fmaf(r[1], scale, -0.5f);
    float y1 = fmaf(r[2], scale, -0.5f);
    float x2 = fmaf(r[3], scale, -0.5f);
    float y2 = fmaf(r[4], scale, -0.5f);
    float bin_h = (y2 - y1) * (1.0f / P);
    float bin_w = (x2 - x1) * (1.0f / P);

    float acc[CPT];
#pragma unroll
    for (int j = 0; j < CPT; ++j) acc[j] = 0.0f;

    const int HW = H * W;
    const float* fp = feat + ((size_t)b * C_CH + (size_t)cg * CPT) * HW;
    const float Hm1 = (float)(H - 1), Wm1 = (float)(W - 1);
    const float Hf = (float)H, Wf = (float)W;

#pragma unroll
    for (int iy = 0; iy < 2; ++iy) {
        float gy = (float)ph + (iy ? 0.75f : 0.25f);
        float yy = fmaf(gy, bin_h, y1);
        bool vy = (yy > -1.0f) && (yy < Hf);
        float yc = fminf(fmaxf(yy, 0.0f), Hm1);
        float y0f = floorf(yc);
        int   y0  = (int)y0f;
        float ly  = yc - y0f, hy = 1.0f - ly;
        int   y1i = min(y0 + 1, H - 1);
        int ro0 = y0 * W, ro1 = y1i * W;
#pragma unroll
        for (int ix = 0; ix < 2; ++ix) {
            float gx = (float)pw + (ix ? 0.75f : 0.25f);
            float xx = fmaf(gx, bin_w, x1);
            bool v = vy && (xx > -1.0f) && (xx < Wf);
            float xc = fminf(fmaxf(xx, 0.0f), Wm1);
            float x0f = floorf(xc);
            int   x0  = (int)x0f;
            float lx  = xc - x0f, hx = 1.0f - lx;
            int   x1i = min(x0 + 1, W - 1);
            float q = v ? 0.25f : 0.0f;
            float w00 = hy * hx * q, w01 = hy * lx * q;
            float w10 = ly * hx * q, w11 = ly * lx * q;
            int o00 = ro0 + x0, o01 = ro0 + x1i;
            int o10 = ro1 + x0, o11 = ro1 + x1i;
#pragma unroll
            for (int j = 0; j < CPT; ++j) {
                const float* pj = fp + j * HW;
                acc[j] = fmaf(w00, pj[o00], acc[j]);
                acc[j] = fmaf(w01, pj[o01], acc[j]);
                acc[j] = fmaf(w10, pj[o10], acc[j]);
                acc[j] = fmaf(w11, pj[o11], acc[j]);
            }
        }
    }

    float* op = out + (((size_t)n * C_CH + (size_t)cg * CPT) * P + ph) * P + pw;
#pragma unroll
    for (int j = 0; j < CPT; ++j) op[(size_t)j * P * P] = acc[j];
}

// ---------------- host ----------------
extern "C" void kernel_launch(void* const* d_in, const int* in_sizes, int n_in,
                              void* d_out, int out_size, void* d_ws, size_t ws_size,
                              hipStream_t stream) {
    const float* feat1 = (const float*)d_in[0];  // (2,256,256,256)
    const float* feat2 = (const float*)d_in[1];  // (2,256,128,128)
    const float* feat3 = (const float*)d_in[2];  // (2,256,64,64)
    const float* rois  = (const float*)d_in[3];  // (N,5)
    const int N = in_sizes[3] / 5;

    float* out1 = (float*)d_out;
    float* out2 = out1 + (size_t)N * C_CH * 28 * 28;
    float* out3 = out2 + (size_t)N * C_CH * 14 * 14;

    const size_t e1 = (size_t)2 * C_CH * 256 * 256;  // elems
    const size_t e2 = (size_t)2 * C_CH * 128 * 128;
    const size_t e3 = (size_t)2 * C_CH * 64 * 64;

    // greedy ws assignment, largest level first
    size_t off = 0;
    float* t1 = nullptr; float* t2 = nullptr; float* t3 = nullptr;
    if (off + e1 * 4 <= ws_size) { t1 = (float*)d_ws + off / 4 * 0 + off / sizeof(float); off += e1 * 4; }
    if (off + e2 * 4 <= ws_size) { t2 = (float*)((char*)d_ws + off); off += e2 * 4; }
    if (off + e3 * 4 <= ws_size) { t3 = (float*)((char*)d_ws + off); off += e3 * 4; }
    if (t1) t1 = (float*)d_ws;  // (t1 is always offset 0 when assigned)

    // transposes
    if (t1) nchw_to_nhwc<<<dim3(65536 / 64, 8), 256, 0, stream>>>(feat1, t1, 65536);
    if (t2) nchw_to_nhwc<<<dim3(16384 / 64, 8), 256, 0, stream>>>(feat2, t2, 16384);
    if (t3) nchw_to_nhwc<<<dim3( 4096 / 64, 8), 256, 0, stream>>>(feat3, t3,  4096);

    // gathers (NHWC path) or direct fallback
    if (t1) {
        roi_gather_nhwc<28, 28><<<dim3(N, 28), 256, 0, stream>>>(t1, rois, out1, 256, 256, 0.25f);
    } else {
        int total = N * (C_CH / 4) * 28 * 28;
        roi_align_direct<28, 4><<<(total + 255) / 256, 256, 0, stream>>>(feat1, rois, out1, N, 256, 256, 0.25f);
    }
    if (t2) {
        roi_gather_nhwc<14, 28><<<dim3(N, 7), 256, 0, stream>>>(t2, rois, out2, 128, 128, 0.125f);
    } else {
        int total = N * (C_CH / 4) * 14 * 14;
        roi_align_direct<14, 4><<<(total + 255) / 256, 256, 0, stream>>>(feat2, rois, out2, N, 128, 128, 0.125f);
    }
    if (t3) {
        roi_gather_nhwc<7, 49><<<dim3(N, 1), 256, 0, stream>>>(t3, rois, out3, 64, 64, 0.0625f);
    } else {
        int total = N * (C_CH / 4) * 7 * 7;
        roi_align_direct<7, 4><<<(total + 255) / 256, 256, 0, stream>>>(feat3, rois, out3, N, 64, 64, 0.0625f);
    }
}

// Round 4
// 423.284 us; speedup vs baseline: 1.1015x; 1.0297x over previous
//
#include <hip/hip_runtime.h>

#define C_CH 256  // channels, fixed by the problem

// ---------------- Phase 1: NCHW -> NHWC transpose ----------------
__global__ __launch_bounds__(256) void nchw_to_nhwc(
    const float* __restrict__ in, float* __restrict__ out, int HW)
{
    __shared__ float lds[64 * 64];
    int ct = blockIdx.y & 3;          // c tile (C_CH/64 = 4)
    int b  = blockIdx.y >> 2;
    int hw0 = blockIdx.x << 6;
    int c0  = ct << 6;
    const float* ip = in  + (size_t)b * C_CH * HW;
    float*       op = out + (size_t)b * HW * C_CH;

    int t   = threadIdx.x;
    int q   = t & 15;
    int r0  = t >> 4;

#pragma unroll
    for (int k = 0; k < 4; ++k) {
        int c_local = r0 + (k << 4);
        const float4 v = *reinterpret_cast<const float4*>(
            ip + (size_t)(c0 + c_local) * HW + hw0 + (q << 2));
#pragma unroll
        for (int i = 0; i < 4; ++i) {
            int hw_local = (q << 2) + i;
            lds[(hw_local << 6) + ((c_local + hw_local) & 63)] = ((const float*)&v)[i];
        }
    }
    __syncthreads();
#pragma unroll
    for (int k = 0; k < 4; ++k) {
        int hw_local = r0 + (k << 4);
        float4 v;
#pragma unroll
        for (int j = 0; j < 4; ++j) {
            int c_local = (q << 2) + j;
            ((float*)&v)[j] = lds[(hw_local << 6) + ((c_local + hw_local) & 63)];
        }
        *reinterpret_cast<float4*>(
            op + (size_t)(hw0 + hw_local) * C_CH + c0 + (q << 2)) = v;
    }
}

// ---------------- weight/offset computation for one sample position ----------
__device__ __forceinline__ void woff16(
    int ph, int pw, float y1, float x1, float bin_h, float bin_w,
    int H, int W, int c4, float* __restrict__ w, int* __restrict__ off)
{
    const float Hm1 = (float)(H - 1), Wm1 = (float)(W - 1);
    const float Hf = (float)H, Wf = (float)W;
#pragma unroll
    for (int iy = 0; iy < 2; ++iy) {
        float gy = (float)ph + (iy ? 0.75f : 0.25f);
        float yy = fmaf(gy, bin_h, y1);
        bool vy = (yy > -1.0f) && (yy < Hf);
        float yc = fminf(fmaxf(yy, 0.0f), Hm1);
        float y0f = floorf(yc);
        int   y0  = (int)y0f;
        float ly  = yc - y0f, hy = 1.0f - ly;
        int   y1i = min(y0 + 1, H - 1);
        int ro0 = y0 * W, ro1 = y1i * W;
#pragma unroll
        for (int ix = 0; ix < 2; ++ix) {
            float gx = (float)pw + (ix ? 0.75f : 0.25f);
            float xx = fmaf(gx, bin_w, x1);
            bool v = vy && (xx > -1.0f) && (xx < Wf);
            float xc = fminf(fmaxf(xx, 0.0f), Wm1);
            float x0f = floorf(xc);
            int   x0  = (int)x0f;
            float lx  = xc - x0f, hx = 1.0f - lx;
            int   x1i = min(x0 + 1, W - 1);
            float q = v ? 0.25f : 0.0f;
            int s = ((iy << 1) + ix) << 2;
            w[s + 0] = hy * hx * q;  off[s + 0] = ((ro0 + x0 ) << 8) + c4;
            w[s + 1] = hy * lx * q;  off[s + 1] = ((ro0 + x1i) << 8) + c4;
            w[s + 2] = ly * hx * q;  off[s + 2] = ((ro1 + x0 ) << 8) + c4;
            w[s + 3] = ly * lx * q;  off[s + 3] = ((ro1 + x1i) << 8) + c4;
        }
    }
}

// ---------------- Phase 2: gather from NHWC ----------------
// Block = 4 waves; wave = one sample position (all 256 ch as float4/lane).
// All 16 corner loads batched -> ONE latency exposure per position.
// LDS tile XOR-swizzled (16B granularity) -> conflict-free write & ~2-way read.
// 1-D grid, XCD-chunked bijective swizzle for per-ROI L2 locality.
template<int P, int POS>
__global__ __launch_bounds__(256, 3) void roi_gather_nhwc(
    const float* __restrict__ nhwc, const float* __restrict__ rois,
    float* __restrict__ out, int H, int W, float scale, int N)
{
    constexpr int PITCH = 260;          // floats; 1040B rows, 16B aligned
    constexpr int NB = (P * P) / POS;   // row-blocks per ROI
    __shared__ float lds[POS * PITCH];

    const int G = N * NB;
    int bid = blockIdx.x;
    int virt = (G % 8 == 0) ? ((bid & 7) * (G >> 3) + (bid >> 3)) : bid;
    int n  = virt / NB;
    int rb = virt - n * NB;
    int ph0 = rb * (POS / P);

    const int lane = threadIdx.x & 63;
    const int wid  = threadIdx.x >> 6;
    const int c4   = lane << 2;

    const float* r = rois + n * 5;
    const int b = (int)r[0];
    const float x1 = fmaf(r[1], scale, -0.5f);
    const float y1 = fmaf(r[2], scale, -0.5f);
    const float x2 = fmaf(r[3], scale, -0.5f);
    const float y2 = fmaf(r[4], scale, -0.5f);
    const float bin_h = (y2 - y1) * (1.0f / P);
    const float bin_w = (x2 - x1) * (1.0f / P);
    const float* fb = nhwc + (size_t)b * H * W * C_CH;

    for (int pos = wid; pos < POS; pos += 4) {
        int ph = ph0 + pos / P;
        int pw = pos % P;

        float w[16];
        int   off[16];
        woff16(ph, pw, y1, x1, bin_h, bin_w, H, W, c4, w, off);

        float4 v[16];
#pragma unroll
        for (int m = 0; m < 16; ++m)
            v[m] = *reinterpret_cast<const float4*>(fb + (size_t)(unsigned)off[m]);
        __builtin_amdgcn_sched_barrier(0);   // keep all 16 loads batched before FMAs

        float4 acc = {0.f, 0.f, 0.f, 0.f};
#pragma unroll
        for (int m = 0; m < 16; ++m) {
            acc.x = fmaf(w[m], v[m].x, acc.x);
            acc.y = fmaf(w[m], v[m].y, acc.y);
            acc.z = fmaf(w[m], v[m].z, acc.z);
            acc.w = fmaf(w[m], v[m].w, acc.w);
        }
        // XOR swizzle at 16B granularity: slot = lane ^ (pos&7)
        int slot = ((c4 >> 2) ^ (pos & 7)) << 2;
        *reinterpret_cast<float4*>(&lds[pos * PITCH + slot]) = acc;
    }
    __syncthreads();

    const size_t obase = (size_t)n * C_CH * (P * P) + (size_t)ph0 * P;
    if constexpr (P != 7) {
        // float4 write-out: per channel, POS floats contiguous & 16B aligned
        constexpr int K4 = POS / 4;
        for (int i = threadIdx.x; i < C_CH * K4; i += 256) {
            int c  = i / K4;
            int k4 = i - c * K4;
            float4 o;
#pragma unroll
            for (int j = 0; j < 4; ++j) {
                int pos = (k4 << 2) + j;
                ((float*)&o)[j] = lds[pos * PITCH + ((((c >> 2) ^ (pos & 7)) << 2) | (c & 3))];
            }
            *reinterpret_cast<float4*>(out + obase + (size_t)c * (P * P) + (k4 << 2)) = o;
        }
    } else {
        for (int i = threadIdx.x; i < C_CH * POS; i += 256) {
            int c   = i / POS;
            int pos = i - c * POS;
            out[obase + (size_t)c * (P * P) + pos] =
                lds[pos * PITCH + ((((c >> 2) ^ (pos & 7)) << 2) | (c & 3))];
        }
    }
}

// ---------------- Fallback: direct NCHW kernel (verified round 2) ----------
template<int P, int CPT>
__global__ __launch_bounds__(256) void roi_align_direct(
    const float* __restrict__ feat, const float* __restrict__ rois,
    float* __restrict__ out, int N, int H, int W, float scale)
{
    constexpr int CG = C_CH / CPT;
    int tid = blockIdx.x * blockDim.x + threadIdx.x;
    int total = N * CG * P * P;
    if (tid >= total) return;

    int pw = tid % P;
    int t  = tid / P;
    int ph = t % P;
    t /= P;
    int cg = t % CG;
    int n  = t / CG;

    const float* r = rois + n * 5;
    int b = (int)r[0];
    float x1 = fmaf(r[1], scale, -0.5f);
    float y1 = fmaf(r[2], scale, -0.5f);
    float x2 = fmaf(r[3], scale, -0.5f);
    float y2 = fmaf(r[4], scale, -0.5f);
    float bin_h = (y2 - y1) * (1.0f / P);
    float bin_w = (x2 - x1) * (1.0f / P);

    float acc[CPT];
#pragma unroll
    for (int j = 0; j < CPT; ++j) acc[j] = 0.0f;

    const int HW = H * W;
    const float* fp = feat + ((size_t)b * C_CH + (size_t)cg * CPT) * HW;

    float w[16]; int off[16];
    woff16(ph, pw, y1, x1, bin_h, bin_w, H, W, 0, w, off);
#pragma unroll
    for (int m = 0; m < 16; ++m) {
        int sp = off[m] >> 8;
#pragma unroll
        for (int j = 0; j < CPT; ++j)
            acc[j] = fmaf(w[m], fp[(size_t)j * HW + sp], acc[j]);
    }

    float* op = out + (((size_t)n * C_CH + (size_t)cg * CPT) * P + ph) * P + pw;
#pragma unroll
    for (int j = 0; j < CPT; ++j) op[(size_t)j * P * P] = acc[j];
}

// ---------------- host ----------------
extern "C" void kernel_launch(void* const* d_in, const int* in_sizes, int n_in,
                              void* d_out, int out_size, void* d_ws, size_t ws_size,
                              hipStream_t stream) {
    const float* feat1 = (const float*)d_in[0];  // (2,256,256,256)
    const float* feat2 = (const float*)d_in[1];  // (2,256,128,128)
    const float* feat3 = (const float*)d_in[2];  // (2,256,64,64)
    const float* rois  = (const float*)d_in[3];  // (N,5)
    const int N = in_sizes[3] / 5;

    float* out1 = (float*)d_out;
    float* out2 = out1 + (size_t)N * C_CH * 28 * 28;
    float* out3 = out2 + (size_t)N * C_CH * 14 * 14;

    const size_t e1 = (size_t)2 * C_CH * 256 * 256;
    const size_t e2 = (size_t)2 * C_CH * 128 * 128;
    const size_t e3 = (size_t)2 * C_CH * 64 * 64;

    size_t off = 0;
    float* t1 = nullptr; float* t2 = nullptr; float* t3 = nullptr;
    if (off + e1 * 4 <= ws_size) { t1 = (float*)((char*)d_ws + off); off += e1 * 4; }
    if (off + e2 * 4 <= ws_size) { t2 = (float*)((char*)d_ws + off); off += e2 * 4; }
    if (off + e3 * 4 <= ws_size) { t3 = (float*)((char*)d_ws + off); off += e3 * 4; }

    if (t1) nchw_to_nhwc<<<dim3(65536 / 64, 8), 256, 0, stream>>>(feat1, t1, 65536);
    if (t2) nchw_to_nhwc<<<dim3(16384 / 64, 8), 256, 0, stream>>>(feat2, t2, 16384);
    if (t3) nchw_to_nhwc<<<dim3( 4096 / 64, 8), 256, 0, stream>>>(feat3, t3,  4096);

    if (t1) {
        roi_gather_nhwc<28, 28><<<N * 28, 256, 0, stream>>>(t1, rois, out1, 256, 256, 0.25f, N);
    } else {
        int total = N * (C_CH / 4) * 28 * 28;
        roi_align_direct<28, 4><<<(total + 255) / 256, 256, 0, stream>>>(feat1, rois, out1, N, 256, 256, 0.25f);
    }
    if (t2) {
        roi_gather_nhwc<14, 28><<<N * 7, 256, 0, stream>>>(t2, rois, out2, 128, 128, 0.125f, N);
    } else {
        int total = N * (C_CH / 4) * 14 * 14;
        roi_align_direct<14, 4><<<(total + 255) / 256, 256, 0, stream>>>(feat2, rois, out2, N, 128, 128, 0.125f);
    }
    if (t3) {
        roi_gather_nhwc<7, 49><<<N * 1, 256, 0, stream>>>(t3, rois, out3, 64, 64, 0.0625f, N);
    } else {
        int total = N * (C_CH / 4) * 7 * 7;
        roi_align_direct<7, 4><<<(total + 255) / 256, 256, 0, stream>>>(feat3, rois, out3, N, 64, 64, 0.0625f);
    }
}